// Round 5
// baseline (6510.245 us; speedup 1.0000x reference)
//
#include <hip/hip_runtime.h>
#include <stdint.h>

#define BB 32
#define CIN 128
#define COUT 256
#define HH 64
#define WW 64
#define TOPK 64
#define NS_D (8.0/255.0)
#define GAP 5e-4          // ambiguity band: ~33x the max fp32 accumulation error
#define EPI_STRIDE 258    // doubles per epilogue pos-row (256 ch + pad)
#define LIST_CAP 65536

typedef __attribute__((address_space(1))) const void glb_void;
typedef __attribute__((address_space(3))) void lds_void;

__device__ __forceinline__ void glds16(const float* g, float* l) {
    __builtin_amdgcn_global_load_lds((glb_void*)g, (lds_void*)l, 16, 0, 0);
}

__device__ __forceinline__ uint64_t sortkey(double v) {
    uint64_t b = (uint64_t)__double_as_longlong(v);
    return (b & 0x8000000000000000ULL) ? ~b : (b | 0x8000000000000000ULL);
}
__device__ __forceinline__ double unsortkey(uint64_t k) {
    uint64_t b = (k & 0x8000000000000000ULL) ? (k & 0x7FFFFFFFFFFFFFFFULL) : ~k;
    return __longlong_as_double((long long)b);
}

// per-wave exact select over 256 keys (4/lane): 64th and 65th largest to all lanes.
__device__ __forceinline__ void select64(const uint64_t u[4], uint64_t& k64, uint64_t& k65) {
    uint64_t prefix = 0;
    for (int bit = 63; bit >= 0; --bit) {
        uint64_t cand = prefix | (1ULL << bit);
        int cnt = (u[0] >= cand) + (u[1] >= cand) + (u[2] >= cand) + (u[3] >= cand);
        for (int m = 1; m < 64; m <<= 1) cnt += __shfl_xor(cnt, m, 64);
        if (cnt >= TOPK) {
            prefix = cand;
            if (cnt == TOPK) break;
        }
    }
    uint64_t mn = ~0ULL, mx = 0ULL;
#pragma unroll
    for (int j = 0; j < 4; ++j) {
        if (u[j] >= prefix) { if (u[j] < mn) mn = u[j]; }
        else                { if (u[j] > mx) mx = u[j]; }
    }
    for (int m = 1; m < 64; m <<= 1) {
        uint64_t a = (uint64_t)__shfl_xor((unsigned long long)mn, m, 64);
        if (a < mn) mn = a;
        uint64_t b = (uint64_t)__shfl_xor((unsigned long long)mx, m, 64);
        if (b > mx) mx = b;
    }
    k64 = mn; k65 = mx;
}

// ---------------- prep A: absw[c] (fp64, coalesced reads) + zero flag counter
__global__ __launch_bounds__(256) void prep_absw(const float* __restrict__ w,
                                                 double* __restrict__ absw,
                                                 int* __restrict__ counter) {
    const int c = blockIdx.x;
    const int t = threadIdx.x;
    if (c == 0 && t == 0) counter[0] = 0;
    double s = 0.0;
    for (int k = t; k < CIN * 9; k += 256) s += fabs((double)w[c * (CIN * 9) + k]);
    __shared__ double red[4];
    for (int m = 32; m; m >>= 1) s += __shfl_xor(s, m, 64);
    if ((t & 63) == 0) red[t >> 6] = s;
    __syncthreads();
    if (t == 0) absw[c] = red[0] + red[1] + red[2] + red[3];
}

// ---------------- prep B: wT[(kh*128+ci)*3+kw][c] = w[c][ci][kh][kw], coalesced writes
__global__ __launch_bounds__(256) void prep_wT(const float* __restrict__ w,
                                               float* __restrict__ wT) {
    const int o0 = blockIdx.x * 16;   // 72 blocks x 16 rows
    const int c = threadIdx.x;
#pragma unroll
    for (int i = 0; i < 16; ++i) {
        int o = o0 + i;
        int kh = o / 384, rem = o - kh * 384, ci = rem / 3, kw = rem - ci * 3;
        wT[(size_t)o * COUT + c] = w[(size_t)(c * CIN + ci) * 9 + kh * 3 + kw];
    }
}

// ---------------- fused: fp32 conv (glds-pipelined) + fp64 epilogue + flagging
__global__ __launch_bounds__(256, 3) void fused_kernel(
    const float* __restrict__ x,
    const float* __restrict__ relu_bias,
    const float* __restrict__ noise,
    const double* __restrict__ absw,
    const float* __restrict__ wT,
    float* __restrict__ out,
    int* __restrict__ counter,
    int* __restrict__ list) {

    __shared__ alignas(16) union {
        struct { float a[2][8 * 68]; float b[2][24 * 256]; } conv;  // 4352 + 49152 = 53504 B
        struct { double o[16 * EPI_STRIDE]; double aw[COUT]; double bi[COUT]; double th[16]; } epi; // 37248 B
    } U;

    const int tid = threadIdx.x;
    const int b = blockIdx.x >> 6;
    const int h = blockIdx.x & 63;

    const int tw = tid & 7;       // position group: p = tw*8 + i
    const int tc = tid >> 3;      // channel group: c = tc*8 + j
    const int lane4 = (tid & 63) * 4;
    const int rg = tid >> 6;      // wave id 0..3
    const int ci0 = tid >> 5;     // A-staging ci row 0..7
    const int w2 = (tid & 31) * 2;

    const int kh_lo = (h == 0) ? 1 : 0;
    const int kh_hi = (h == HH - 1) ? 1 : 2;
    const int nstages = (kh_hi - kh_lo + 1) * 16;

    float acc[8][8];
#pragma unroll
    for (int i = 0; i < 8; ++i)
#pragma unroll
        for (int j = 0; j < 8; ++j) acc[i][j] = 0.f;

    // A halos are always zero: write once for both buffers
    if (tid < 16) {
        int bufi = tid >> 3, ci = tid & 7;
        U.conv.a[bufi][ci * 68 + 0] = 0.f;
        U.conv.a[bufi][ci * 68 + 65] = 0.f;
    }

    // prologue: stage s=0 (kh=kh_lo, cib=0) into buffer 0
    {
        const int r0 = h + kh_lo - 1;
        float2 av = *(const float2*)&x[(((size_t)(b * CIN) + ci0) * HH + r0) * WW + w2];
        U.conv.a[0][ci0 * 68 + 1 + w2] = av.x;
        U.conv.a[0][ci0 * 68 + 2 + w2] = av.y;
        const float* bs = wT + (size_t)(kh_lo * CIN) * 768 + rg * 256 + lane4;
#pragma unroll
        for (int j = 0; j < 6; ++j)
            glds16(bs + j * 1024, &U.conv.b[0][(rg + 4 * j) * 256 + lane4]);
    }
    __syncthreads();

    int p = 0;
#pragma unroll 1
    for (int s = 0; s < nstages; ++s) {
        const bool havenext = (s + 1 < nstages);
        float2 a_next = {0.f, 0.f};
        if (havenext) {
            const int kh_n = kh_lo + ((s + 1) >> 4);
            const int cib_n = ((s + 1) & 15) * 8;
            const int rn = h + kh_n - 1;
            // prefetch B(s+1) direct-to-LDS (completes during compute below)
            const float* bs = wT + (size_t)(kh_n * CIN + cib_n) * 768 + rg * 256 + lane4;
#pragma unroll
            for (int j = 0; j < 6; ++j)
                glds16(bs + j * 1024, &U.conv.b[p ^ 1][(rg + 4 * j) * 256 + lane4]);
            // prefetch A(s+1) to regs
            a_next = *(const float2*)&x[(((size_t)(b * CIN + cib_n) + ci0) * HH + rn) * WW + w2];
        }
        // compute stage s
        const float* Ap = U.conv.a[p];
        const float* Bp = U.conv.b[p];
#pragma unroll
        for (int ci_l = 0; ci_l < 8; ++ci_l) {
            float win[12];
#pragma unroll
            for (int q = 0; q < 3; ++q)
                *(float4*)&win[q * 4] = *(const float4*)&Ap[ci_l * 68 + tw * 8 + q * 4];
            float bw[3][8];
#pragma unroll
            for (int kw = 0; kw < 3; ++kw) {
                *(float4*)&bw[kw][0] = *(const float4*)&Bp[(ci_l * 3 + kw) * 256 + tc * 8];
                *(float4*)&bw[kw][4] = *(const float4*)&Bp[(ci_l * 3 + kw) * 256 + tc * 8 + 4];
            }
#pragma unroll
            for (int kw = 0; kw < 3; ++kw)
#pragma unroll
                for (int i = 0; i < 8; ++i)
#pragma unroll
                    for (int j = 0; j < 8; ++j)
                        acc[i][j] = fmaf(win[i + kw], bw[kw][j], acc[i][j]);
        }
        if (havenext) {
            U.conv.a[p ^ 1][ci0 * 68 + 1 + w2] = a_next.x;
            U.conv.a[p ^ 1][ci0 * 68 + 2 + w2] = a_next.y;
        }
        __syncthreads();
        p ^= 1;
    }

    // ---------- epilogue: four 16-position passes, fp64 from here on
    U.epi.aw[tid] = absw[tid];
    U.epi.bi[tid] = (double)relu_bias[tid];

    for (int q = 0; q < 4; ++q) {
        __syncthreads();
        // phase 1: scatter promoted acc -> U.epi.o[pos_local][ch]
        if ((tw >> 1) == q) {
            int pl0 = (tw & 1) * 8;
#pragma unroll
            for (int i = 0; i < 8; ++i)
#pragma unroll
                for (int m = 0; m < 4; ++m) {
                    double2 d = { (double)acc[i][2 * m], (double)acc[i][2 * m + 1] };
                    *(double2*)&U.epi.o[(pl0 + i) * EPI_STRIDE + tc * 8 + 2 * m] = d;
                }
        }
        __syncthreads();
        // phase 2: add noise (fp64)
        {
            int wl = tid & 15;
            int cg = tid >> 4;  // 0..15
            int wg = q * 16 + wl;
#pragma unroll 4
            for (int it = 0; it < 16; ++it) {
                int c = cg + 16 * it;
                double u = (double)noise[((size_t)(b * COUT + c) * HH + h) * WW + wg];
                U.epi.o[wl * EPI_STRIDE + c] += U.epi.aw[c] * NS_D * (2.0 * u - 1.0);
            }
        }
        __syncthreads();
        // phase 3: exact 64th/65th per position; flag ambiguous pixels
        {
            int lane = tid & 63;
#pragma unroll 1
            for (int pp = 0; pp < 4; ++pp) {
                int pl = rg * 4 + pp;  // 0..15
                uint64_t u[4];
#pragma unroll
                for (int j = 0; j < 4; ++j)
                    u[j] = sortkey(U.epi.o[pl * EPI_STRIDE + lane + 64 * j]);
                uint64_t k64, k65;
                select64(u, k64, k65);
                if (lane == 0) {
                    double t64 = unsortkey(k64);
                    U.epi.th[pl] = t64;
                    if (t64 - unsortkey(k65) < GAP) {
                        int idx = atomicAdd(counter, 1);
                        if (idx < LIST_CAP) list[idx] = (b << 12) | (h << 6) | (q * 16 + pl);
                    }
                }
            }
        }
        __syncthreads();
        // phase 4: threshold (>=), +bias, relu, cast to fp32, store
        {
            int wl = tid & 15;
            int cg = tid >> 4;
            int wg = q * 16 + wl;
            double tf = U.epi.th[wl];
#pragma unroll 4
            for (int it = 0; it < 16; ++it) {
                int c = cg + 16 * it;
                double v = U.epi.o[wl * EPI_STRIDE + c];
                double o = (v >= tf ? v : 0.0) + U.epi.bi[c];
                out[((size_t)(b * COUT + c) * HH + h) * WW + wg] = (float)fmax(o, 0.0);
            }
        }
    }
}

// ---------------- fixup: exact fp64 recompute of flagged pixels, 4 per block
__global__ __launch_bounds__(256, 2) void fixup_kernel(
    const float* __restrict__ x,
    const float* __restrict__ wT,       // [(kh*128+ci)*3+kw][c]
    const float* __restrict__ relu_bias,
    const float* __restrict__ noise,
    const double* __restrict__ absw,
    float* __restrict__ out,
    const int* __restrict__ counter,
    const int* __restrict__ list) {

    __shared__ double xs[4][CIN * 9];     // 36864 B, row order == wT row order
    __shared__ uint64_t keys[4][COUT];    // 8192 B

    int n = counter[0];
    if (n > LIST_CAP) n = LIST_CAP;

    for (int base = blockIdx.x * 4; base < n; base += gridDim.x * 4) {
        const int np = min(4, n - base);
        __syncthreads();
        // stage patches in wT row order: row o = kh*384 + ci*3 + kw
        for (int q = 0; q < np; ++q) {
            int pix = list[base + q];
            int bb = pix >> 12, hh = (pix >> 6) & 63, ww = pix & 63;
            for (int t = threadIdx.x; t < CIN * 9; t += 256) {
                int kh = t / 384, rem = t - kh * 384, ci = rem / 3, kw = rem - ci * 3;
                int hr = hh + kh - 1, wr = ww + kw - 1;
                xs[q][t] = (hr >= 0 && hr < HH && wr >= 0 && wr < WW)
                    ? (double)x[(((size_t)(bb * CIN + ci) * HH + hr) * WW) + wr] : 0.0;
            }
        }
        __syncthreads();
        const int c = threadIdx.x;
        double s[4] = {0.0, 0.0, 0.0, 0.0};
        for (int row = 0; row < CIN * 9; ++row) {
            double wv = (double)wT[(size_t)row * COUT + c];   // coalesced
            s[0] = fma(wv, xs[0][row], s[0]);
            s[1] = fma(wv, xs[1][row], s[1]);
            s[2] = fma(wv, xs[2][row], s[2]);
            s[3] = fma(wv, xs[3][row], s[3]);
        }
#pragma unroll 1
        for (int q = 0; q < np; ++q) {
            int pix = list[base + q];
            int bb = pix >> 12, hh = (pix >> 6) & 63, ww = pix & 63;
            double u = (double)noise[(((size_t)(bb * COUT + c) * HH + hh) * WW) + ww];
            s[q] += absw[c] * NS_D * (2.0 * u - 1.0);
            keys[q][c] = sortkey(s[q]);
        }
        __syncthreads();
#pragma unroll 1
        for (int q = 0; q < np; ++q) {
            uint64_t uu[4];
            int lane = threadIdx.x & 63;
#pragma unroll
            for (int j = 0; j < 4; ++j) uu[j] = keys[q][lane + 64 * j];
            uint64_t k64, k65;
            select64(uu, k64, k65);   // all 4 waves compute identically
            double t64 = unsortkey(k64);
            int pix = list[base + q];
            int bb = pix >> 12, hh = (pix >> 6) & 63, ww = pix & 63;
            double o = (s[q] >= t64 ? s[q] : 0.0) + (double)relu_bias[c];
            out[(((size_t)(bb * COUT + c) * HH + hh) * WW) + ww] = (float)fmax(o, 0.0);
        }
    }
}

extern "C" void kernel_launch(void* const* d_in, const int* in_sizes, int n_in,
                              void* d_out, int out_size, void* d_ws, size_t ws_size,
                              hipStream_t stream) {
    const float* x         = (const float*)d_in[0];
    const float* weight    = (const float*)d_in[1];
    const float* relu_bias = (const float*)d_in[2];
    const float* noise_u   = (const float*)d_in[3];
    float* out = (float*)d_out;

    char* ws = (char*)d_ws;
    double* absw  = (double*)ws;                              // 2 KB
    float*  wT    = (float*)(ws + 2048);                      // 1,179,648 B
    int*    cnt   = (int*)(ws + 2048 + 1179648);              // 16 B slot
    int*    list  = (int*)(ws + 2048 + 1179648 + 16);         // 256 KB

    prep_absw<<<COUT, 256, 0, stream>>>(weight, absw, cnt);
    prep_wT<<<72, 256, 0, stream>>>(weight, wT);
    fused_kernel<<<BB * HH, 256, 0, stream>>>(x, relu_bias, noise_u, absw, wT, out, cnt, list);
    fixup_kernel<<<512, 256, 0, stream>>>(x, wT, relu_bias, noise_u, absw, out, cnt, list);
}

// Round 6
// 1372.771 us; speedup vs baseline: 4.7424x; 4.7424x over previous
//
#include <hip/hip_runtime.h>
#include <stdint.h>

#define BB 32
#define CIN 128
#define COUT 256
#define HH 64
#define WW 64
#define TOPK 64
#define NS_D (8.0/255.0)
#define GAP 5e-4          // ambiguity band: ~33x the max fp32 accumulation error
#define EPI_STRIDE 258    // doubles per epilogue pos-row (256 ch + pad)
#define LIST_CAP 65536

__device__ __forceinline__ uint64_t sortkey(double v) {
    uint64_t b = (uint64_t)__double_as_longlong(v);
    return (b & 0x8000000000000000ULL) ? ~b : (b | 0x8000000000000000ULL);
}
__device__ __forceinline__ double unsortkey(uint64_t k) {
    uint64_t b = (k & 0x8000000000000000ULL) ? (k & 0x7FFFFFFFFFFFFFFFULL) : ~k;
    return __longlong_as_double((long long)b);
}

// per-wave exact select over 256 keys (4/lane): 64th and 65th largest to all lanes.
// ballot+popcount per bit (no LDS-pipe shuffles in the descent).
__device__ __forceinline__ void select64(const uint64_t u[4], uint64_t& k64, uint64_t& k65) {
    uint64_t prefix = 0;
    for (int bit = 63; bit >= 0; --bit) {
        uint64_t cand = prefix | (1ULL << bit);
        int cnt = __popcll(__ballot(u[0] >= cand)) + __popcll(__ballot(u[1] >= cand))
                + __popcll(__ballot(u[2] >= cand)) + __popcll(__ballot(u[3] >= cand));
        if (cnt >= TOPK) {
            prefix = cand;
            if (cnt == TOPK) break;
        }
    }
    uint64_t mn = ~0ULL, mx = 0ULL;
#pragma unroll
    for (int j = 0; j < 4; ++j) {
        if (u[j] >= prefix) { if (u[j] < mn) mn = u[j]; }
        else                { if (u[j] > mx) mx = u[j]; }
    }
    for (int m = 1; m < 64; m <<= 1) {
        uint64_t a = (uint64_t)__shfl_xor((unsigned long long)mn, m, 64);
        if (a < mn) mn = a;
        uint64_t b = (uint64_t)__shfl_xor((unsigned long long)mx, m, 64);
        if (b > mx) mx = b;
    }
    k64 = mn; k65 = mx;
}

// ---------------- prep A: absw[c] (fp64, coalesced reads) + zero flag counter
__global__ __launch_bounds__(256) void prep_absw(const float* __restrict__ w,
                                                 double* __restrict__ absw,
                                                 int* __restrict__ counter) {
    const int c = blockIdx.x;
    const int t = threadIdx.x;
    if (c == 0 && t == 0) counter[0] = 0;
    double s = 0.0;
    for (int k = t; k < CIN * 9; k += 256) s += fabs((double)w[c * (CIN * 9) + k]);
    __shared__ double red[4];
    for (int m = 32; m; m >>= 1) s += __shfl_xor(s, m, 64);
    if ((t & 63) == 0) red[t >> 6] = s;
    __syncthreads();
    if (t == 0) absw[c] = red[0] + red[1] + red[2] + red[3];
}

// ---------------- prep B: wT[((kh*3+kw)*128+ci)][c] = w[c][ci][kh][kw], coalesced writes
__global__ __launch_bounds__(256) void prep_wT(const float* __restrict__ w,
                                               float* __restrict__ wT) {
    const int o0 = blockIdx.x * 16;   // 72 blocks x 16 rows, rows o = r*128+ci, r=kh*3+kw
    const int c = threadIdx.x;
#pragma unroll
    for (int i = 0; i < 16; ++i) {
        int o = o0 + i;
        int r = o >> 7, ci = o & 127;
        wT[(size_t)o * COUT + c] = w[(size_t)(c * CIN + ci) * 9 + r];
    }
}

// ---------------- fused: fp32 conv + fp64-promoted epilogue + ambiguity flagging
__global__ __launch_bounds__(256, 4) void fused_kernel(
    const float* __restrict__ x,
    const float* __restrict__ relu_bias,
    const float* __restrict__ noise,
    const double* __restrict__ absw,
    const float* __restrict__ wT,
    float* __restrict__ out,
    int* __restrict__ counter,
    int* __restrict__ list) {

    __shared__ alignas(16) union {
        struct { float a[8 * 68]; float b[24 * 256]; } conv;  // 2176B + 24576B
        struct { double o[16 * EPI_STRIDE]; } epi;            // 33024B
    } U;
    __shared__ double lds_absw[COUT];
    __shared__ double lds_bias[COUT];
    __shared__ double thr[16];

    const int tid = threadIdx.x;
    const int b = blockIdx.x >> 6;
    const int h = blockIdx.x & 63;

    const int tw = tid & 7;   // position group: p = tw*8 + i
    const int tc = tid >> 3;  // channel group: c = tc*8 + j   (0..31)

    lds_absw[tid] = absw[tid];
    lds_bias[tid] = (double)relu_bias[tid];

    float acc[8][8];
#pragma unroll
    for (int i = 0; i < 8; ++i)
#pragma unroll
        for (int j = 0; j < 8; ++j) acc[i][j] = 0.f;

    // ---------- fp32 GEMM: K = (kh, ci, kw)
    for (int kh = 0; kh < 3; ++kh) {
        const int r = h + kh - 1;
        if (r < 0 || r >= HH) continue;  // uniform per block
        for (int cib = 0; cib < CIN; cib += 8) {
            __syncthreads();
            // stage A: x[b, cib..cib+7, r, 0..63] with halo zeros
            {
                int ci_l = tid >> 5;          // 0..7
                int w2 = (tid & 31) * 2;      // 0..62
                const float* xp = x + (((size_t)(b * CIN + cib + ci_l) * HH + r) * WW) + w2;
                float2 v = *(const float2*)xp;
                U.conv.a[ci_l * 68 + 1 + w2] = v.x;
                U.conv.a[ci_l * 68 + 2 + w2] = v.y;
                if ((tid & 31) == 0) { U.conv.a[ci_l * 68 + 0] = 0.f; U.conv.a[ci_l * 68 + 65] = 0.f; }
            }
            // stage B: wT row (kh*3+kw)*128 + (cib+ci_l) -> U.conv.b[(ci_l*3+kw)*256 + c]
            {
                int c4 = (tid & 63) * 4;
                int rg = tid >> 6;  // 0..3
#pragma unroll
                for (int j = 0; j < 6; ++j) {
                    int row = rg + 4 * j;       // 0..23 == ci_l*3 + kw
                    int ci_l = row / 3, kw = row % 3;
                    float4 v = *(const float4*)&wT[((size_t)((kh * 3 + kw) * CIN) + cib + ci_l) * COUT + c4];
                    *(float4*)&U.conv.b[row * 256 + c4] = v;
                }
            }
            __syncthreads();
#pragma unroll
            for (int ci_l = 0; ci_l < 8; ++ci_l) {
                float win[12];
#pragma unroll
                for (int q = 0; q < 3; ++q)
                    *(float4*)&win[q * 4] = *(const float4*)&U.conv.a[ci_l * 68 + tw * 8 + q * 4];
                float bw[3][8];
#pragma unroll
                for (int kw = 0; kw < 3; ++kw) {
                    *(float4*)&bw[kw][0] = *(const float4*)&U.conv.b[(ci_l * 3 + kw) * 256 + tc * 8];
                    *(float4*)&bw[kw][4] = *(const float4*)&U.conv.b[(ci_l * 3 + kw) * 256 + tc * 8 + 4];
                }
#pragma unroll
                for (int kw = 0; kw < 3; ++kw)
#pragma unroll
                    for (int i = 0; i < 8; ++i)
#pragma unroll
                        for (int j = 0; j < 8; ++j)
                            acc[i][j] = fmaf(win[i + kw], bw[kw][j], acc[i][j]);
            }
        }
    }

    // ---------- epilogue: four 16-position passes, fp64 from here on
    for (int q = 0; q < 4; ++q) {
        __syncthreads();
        // phase 1: scatter promoted acc -> U.epi.o[pos_local][ch]
        if ((tw >> 1) == q) {
            int pl0 = (tw & 1) * 8;
#pragma unroll
            for (int i = 0; i < 8; ++i)
#pragma unroll
                for (int m = 0; m < 4; ++m) {
                    double2 d = { (double)acc[i][2 * m], (double)acc[i][2 * m + 1] };
                    *(double2*)&U.epi.o[(pl0 + i) * EPI_STRIDE + tc * 8 + 2 * m] = d;
                }
        }
        __syncthreads();
        // phase 2: add noise (fp64)
        {
            int wl = tid & 15;
            int cg = tid >> 4;  // 0..15
            int wg = q * 16 + wl;
#pragma unroll 4
            for (int it = 0; it < 16; ++it) {
                int c = cg + 16 * it;
                double u = (double)noise[((size_t)(b * COUT + c) * HH + h) * WW + wg];
                U.epi.o[wl * EPI_STRIDE + c] += lds_absw[c] * NS_D * (2.0 * u - 1.0);
            }
        }
        __syncthreads();
        // phase 3: exact 64th/65th per position; flag ambiguous pixels
        {
            int wave = tid >> 6;
            int lane = tid & 63;
#pragma unroll 1
            for (int pp = 0; pp < 4; ++pp) {
                int pl = wave * 4 + pp;  // 0..15
                uint64_t u[4];
#pragma unroll
                for (int j = 0; j < 4; ++j)
                    u[j] = sortkey(U.epi.o[pl * EPI_STRIDE + lane + 64 * j]);
                uint64_t k64, k65;
                select64(u, k64, k65);
                if (lane == 0) {
                    double t64 = unsortkey(k64);
                    thr[pl] = t64;
                    if (t64 - unsortkey(k65) < GAP) {
                        int idx = atomicAdd(counter, 1);
                        if (idx < LIST_CAP) list[idx] = (b << 12) | (h << 6) | (q * 16 + pl);
                    }
                }
            }
        }
        __syncthreads();
        // phase 4: threshold (>=), +bias, relu, cast to fp32, store
        {
            int wl = tid & 15;
            int cg = tid >> 4;
            int wg = q * 16 + wl;
            double tf = thr[wl];
#pragma unroll 4
            for (int it = 0; it < 16; ++it) {
                int c = cg + 16 * it;
                double v = U.epi.o[wl * EPI_STRIDE + c];
                double o = (v >= tf ? v : 0.0) + lds_bias[c];
                out[((size_t)(b * COUT + c) * HH + h) * WW + wg] = (float)fmax(o, 0.0);
            }
        }
    }
}

// ---------------- fixup: exact fp64 recompute of flagged pixels, 4 per block
__global__ __launch_bounds__(256, 2) void fixup_kernel(
    const float* __restrict__ x,
    const float* __restrict__ wT,       // [(kh*3+kw)*128+ci][c]
    const float* __restrict__ relu_bias,
    const float* __restrict__ noise,
    const double* __restrict__ absw,
    float* __restrict__ out,
    const int* __restrict__ counter,
    const int* __restrict__ list) {

    __shared__ double xs[4][CIN * 9];     // 36864 B, row order == wT row order
    __shared__ uint64_t keys[4][COUT];    // 8192 B

    int n = counter[0];
    if (n > LIST_CAP) n = LIST_CAP;

    for (int base = blockIdx.x * 4; base < n; base += gridDim.x * 4) {
        const int np = min(4, n - base);
        __syncthreads();
        // stage patches in wT row order: row t = (kh*3+kw)*128 + ci
        for (int q = 0; q < np; ++q) {
            int pix = list[base + q];
            int bb = pix >> 12, hh = (pix >> 6) & 63, ww = pix & 63;
            for (int t = threadIdx.x; t < CIN * 9; t += 256) {
                int r = t >> 7, ci = t & 127;
                int kh = r / 3, kw = r % 3;
                int hr = hh + kh - 1, wr = ww + kw - 1;
                xs[q][t] = (hr >= 0 && hr < HH && wr >= 0 && wr < WW)
                    ? (double)x[(((size_t)(bb * CIN + ci) * HH + hr) * WW) + wr] : 0.0;
            }
        }
        __syncthreads();
        const int c = threadIdx.x;
        double s[4] = {0.0, 0.0, 0.0, 0.0};
        for (int row = 0; row < CIN * 9; ++row) {
            double wv = (double)wT[(size_t)row * COUT + c];   // coalesced
            s[0] = fma(wv, xs[0][row], s[0]);
            s[1] = fma(wv, xs[1][row], s[1]);
            s[2] = fma(wv, xs[2][row], s[2]);
            s[3] = fma(wv, xs[3][row], s[3]);
        }
#pragma unroll 1
        for (int q = 0; q < np; ++q) {
            int pix = list[base + q];
            int bb = pix >> 12, hh = (pix >> 6) & 63, ww = pix & 63;
            double u = (double)noise[(((size_t)(bb * COUT + c) * HH + hh) * WW) + ww];
            s[q] += absw[c] * NS_D * (2.0 * u - 1.0);
            keys[q][c] = sortkey(s[q]);
        }
        __syncthreads();
#pragma unroll 1
        for (int q = 0; q < np; ++q) {
            uint64_t uu[4];
            int lane = threadIdx.x & 63;
#pragma unroll
            for (int j = 0; j < 4; ++j) uu[j] = keys[q][lane + 64 * j];
            uint64_t k64, k65;
            select64(uu, k64, k65);   // all 4 waves compute identically
            double t64 = unsortkey(k64);
            int pix = list[base + q];
            int bb = pix >> 12, hh = (pix >> 6) & 63, ww = pix & 63;
            double o = (s[q] >= t64 ? s[q] : 0.0) + (double)relu_bias[c];
            out[(((size_t)(bb * COUT + c) * HH + hh) * WW) + ww] = (float)fmax(o, 0.0);
        }
    }
}

extern "C" void kernel_launch(void* const* d_in, const int* in_sizes, int n_in,
                              void* d_out, int out_size, void* d_ws, size_t ws_size,
                              hipStream_t stream) {
    const float* x         = (const float*)d_in[0];
    const float* weight    = (const float*)d_in[1];
    const float* relu_bias = (const float*)d_in[2];
    const float* noise_u   = (const float*)d_in[3];
    float* out = (float*)d_out;

    char* ws = (char*)d_ws;
    double* absw  = (double*)ws;                              // 2 KB
    float*  wT    = (float*)(ws + 2048);                      // 1,179,648 B
    int*    cnt   = (int*)(ws + 2048 + 1179648);              // 16 B slot
    int*    list  = (int*)(ws + 2048 + 1179648 + 16);         // 256 KB

    prep_absw<<<COUT, 256, 0, stream>>>(weight, absw, cnt);
    prep_wT<<<72, 256, 0, stream>>>(weight, wT);
    fused_kernel<<<BB * HH, 256, 0, stream>>>(x, relu_bias, noise_u, absw, wT, out, cnt, list);
    fixup_kernel<<<512, 256, 0, stream>>>(x, wT, relu_bias, noise_u, absw, out, cnt, list);
}